// Round 2
// baseline (244.026 us; speedup 1.0000x reference)
//
#include <hip/hip_runtime.h>

// Correlation / cost-volume, fp32.
// corr[b, dy*9+dx, y, x] = (1/128) * sum_c in1[b,c,y,x] * in2[b,c,y+dy-4,x+dx-4]
//
// R9 = R8 (counted-vmcnt pipeline, never benched - infra timeout) with the
// DMA slot map cleaned up so the wait is branch-free:
//   8 slots over waves 0..3 (2 each, s = wv*2+it); wave 4 issues none.
//   => every wave's steady-state outstanding is 4 (or 0) and a single
//   unconditional WAITBAR(2) is correct for all waves (trivial for wave 4).
//   Removes the divergent if(wv<3) around s_barrier (predication there
//   would over-drain chunk k+2 and re-serialize the pipe).
// Theory unchanged: R7's 201 us ~ 7x the ~25 us VALU floor because its
// __syncthreads() lowers to s_waitcnt vmcnt(0) right after issuing the
// next chunk's global_load_lds -> full HBM latency serialized per chunk.
// Here: 3-buffer depth-2 prefetch, "s_waitcnt vmcnt(2) lgkmcnt(0);
// s_barrier" (never 0 in steady state). CC=1 -> 3 x 8 KB = 24 KB/block,
// 2 blocks/CU co-resident. Inner loop unchanged (DPP x-halos, pitch-132,
// 72 FMA per thread-chunk).

#define MAXD 4
#define ND 9
#define NDISP 81
#define BATCH 8
#define CH 128
#define HH 128
#define WW 128
#define HW (HH * WW)
#define CC 1                      // channels per chunk
#define NCHUNK (CH / CC)          // 128
#define TY 2
#define NROW (TY + 2 * MAXD)      // 10 staged in2 rows
#define PITCH 132                 // 128 px + 4 pad floats (banks)
#define CPC2 (NROW * PITCH)       // 1320 floats per in2 chunk
#define IN2SLOTS 6                // ceil(1320/256) 1-KB DMA slots
#define IN1OFF (IN2SLOTS * 256)   // 1536: in1 region base (floats)
#define CPL1 PITCH                // 132 floats per in1 row
#define IN1F (TY * CPL1)          // 264 floats in1 per chunk
#define NSLOT 8                   // 6 in2 + 2 in1 1-KB DMA slots
#define BUFF (NSLOT * 256)        // 2048 floats per buffer (8 KB)
#define NBUF 3
#define NT 320                    // 5 waves; threads 0..287 compute
#define NACT 288                  // (ly:2)(dy:9)(xg:16)
#define DMAWAVES 4                // waves 0..3 own 2 slots each

typedef const __attribute__((address_space(1))) float GAS;
typedef __attribute__((address_space(3))) float LAS;

__device__ __forceinline__ void dma16(const float* g, float* l) {
    __builtin_amdgcn_global_load_lds((GAS*)g, (LAS*)l, 16, 0, 0);
}
__device__ __forceinline__ float dpp_shr1(float x) {   // lane i <- lane i-1
    return __int_as_float(__builtin_amdgcn_update_dpp(
        0, __float_as_int(x), 0x111, 0xF, 0xF, true));
}
__device__ __forceinline__ float dpp_shl1(float x) {   // lane i <- lane i+1
    return __int_as_float(__builtin_amdgcn_update_dpp(
        0, __float_as_int(x), 0x101, 0xF, 0xF, true));
}

// Fused counted-wait + barrier. lgkmcnt(0) guarantees this wave's ds_reads
// of the rotating buffers completed before the barrier, so the next
// iteration's DMA into buffer (k+2)%3 cannot race any wave's reads of it.
// vmcnt(N) drains exactly the oldest (outstanding-N) loads (in-order).
#define WAITBAR(N) asm volatile( \
    "s_waitcnt vmcnt(" #N ") lgkmcnt(0)\n\ts_barrier" ::: "memory")

__global__ __launch_bounds__(NT, 2) void corr_kernel(
    const float* __restrict__ in1,
    const float* __restrict__ in2,
    float* __restrict__ out)
{
    __shared__ float s2[NBUF][BUFF];   // 3 x 8192 B = 24576 B

    const int tid = threadIdx.x;
    const int b   = blockIdx.x;
    const int y0  = blockIdx.y * TY;

    const bool act = tid < NACT;
    const int xg   = tid & 15;              // 16 lanes span the 128-px row
    const int dy   = (tid >> 4) % ND;
    const int ly   = act ? (tid / 144) : 0; // pad threads use valid addrs
    const int lane = tid & 63;
    const int rl   = ly + dy;               // staged in2 row consumed
    const bool rok = (unsigned)(y0 + rl - MAXD) < (unsigned)HH;

    const float* in1b = in1 + (size_t)b * CH * HW;
    const float* in2b = in2 + (size_t)b * CH * HW;

    // ---- DMA slot sources: waves 0..3 own slots {2w, 2w+1}; wave 4 none.
    const int wv = __builtin_amdgcn_readfirstlane(tid >> 6);   // 0..4
    const bool dmaw = (wv < DMAWAVES);
    const float* gsrc[2];
    int ldsoff[2];
    #pragma unroll
    for (int it = 0; it < 2; ++it) {
        int ss = dmaw ? (wv * 2 + it) : 0;   // 0..7
        ldsoff[it] = ss * 256;
        if (ss < IN2SLOTS) {
            // in2 region: flat F -> [R][132]
            int F = ss * 256 + lane * 4;
            int R = F / PITCH;
            int j = F - R * PITCH;          // 16B chunks: j in {0,4,...,128}
            bool v = (F < CPC2) && (j < WW);
            int rr = y0 - MAXD + R;
            int sr = rr < 0 ? 0 : (rr >= HH ? HH - 1 : rr);  // garbage OK
            gsrc[it] = in2b + (v ? ((size_t)sr * WW + j) : 0);
        } else {
            // in1 region: flat F -> [ly][132]
            int F   = (ss - IN2SLOTS) * 256 + lane * 4;
            bool v  = F < IN1F;
            int Fc  = v ? F : 0;
            int ly_ = Fc / CPL1;
            int j   = Fc - ly_ * CPL1;
            v = v && (j < WW);
            gsrc[it] = in1b + (v ? ((size_t)(y0 + ly_) * WW + j) : 0);
        }
    }

    float acc[ND][8];
    #pragma unroll
    for (int d = 0; d < ND; ++d)
        #pragma unroll
        for (int i = 0; i < 8; ++i) acc[d][i] = 0.0f;

    // ---- prologue: DMA chunks 0,1 into buffers 0,1; drain chunk 0 ----
    if (dmaw) {
        #pragma unroll
        for (int it = 0; it < 2; ++it) dma16(gsrc[it], &s2[0][ldsoff[it]]);
        #pragma unroll
        for (int it = 0; it < 2; ++it) gsrc[it] += CC * HW;
        #pragma unroll
        for (int it = 0; it < 2; ++it) dma16(gsrc[it], &s2[1][ldsoff[it]]);
        #pragma unroll
        for (int it = 0; it < 2; ++it) gsrc[it] += CC * HW;
    }
    WAITBAR(2);

    #pragma unroll 1
    for (int k = 0; k < NCHUNK; ++k) {
        const int p = k % 3;

        // DMA chunk k+2 (stays in flight across >= 1 full chunk of compute)
        if (k + 2 < NCHUNK && dmaw) {
            const int pn = (k + 2) % 3;
            #pragma unroll
            for (int it = 0; it < 2; ++it)
                dma16(gsrc[it], &s2[pn][ldsoff[it]]);
            #pragma unroll
            for (int it = 0; it < 2; ++it) gsrc[it] += CC * HW;
        }

        // ---- compute chunk k ----
        {
            const float* sp = &s2[p][rl * PITCH + xg * 8];
            float4 wlo = *(const float4*)(sp);
            float4 whi = *(const float4*)(sp + 4);
            float w[8] = {wlo.x, wlo.y, wlo.z, wlo.w,
                          whi.x, whi.y, whi.z, whi.w};

            float W[16];
            W[0]  = dpp_shr1(w[4]);   // x-4 from lane-1; 0 at image edge
            W[1]  = dpp_shr1(w[5]);
            W[2]  = dpp_shr1(w[6]);
            W[3]  = dpp_shr1(w[7]);
            #pragma unroll
            for (int i = 0; i < 8; ++i) W[4 + i] = w[i];
            W[12] = dpp_shl1(w[0]);   // x+8 from lane+1; 0 at image edge
            W[13] = dpp_shl1(w[1]);
            W[14] = dpp_shl1(w[2]);
            W[15] = dpp_shl1(w[3]);

            const float* apx = &s2[p][IN1OFF + ly * CPL1 + xg * 8];
            float4 a0 = *(const float4*)(apx);
            float4 a1 = *(const float4*)(apx + 4);
            float a[8] = {a0.x, a0.y, a0.z, a0.w, a1.x, a1.y, a1.z, a1.w};

            #pragma unroll
            for (int d = 0; d < ND; ++d)
                #pragma unroll
                for (int i = 0; i < 8; ++i)
                    acc[d][i] = fmaf(a[i], W[i + d], acc[d][i]);
        }

        // ---- counted wait: chunk k+1 resident, chunk k+2 stays in flight
        if (k + 2 < NCHUNK) {
            WAITBAR(2);
        } else if (k + 1 < NCHUNK) {
            WAITBAR(0);   // tail: only chunk k+1 outstanding
        }
    }

    // ---- epilogue: mean over C; OOB rows scale to exact zero ----
    if (act) {
        const float sc = rok ? (1.0f / (float)CH) : 0.0f;
        float* outb = out + (size_t)b * NDISP * HW
                          + (size_t)(y0 + ly) * WW + xg * 8;
        #pragma unroll
        for (int d = 0; d < ND; ++d) {
            float* op = outb + (size_t)(dy * ND + d) * HW;
            float4 v0 = make_float4(acc[d][0] * sc, acc[d][1] * sc,
                                    acc[d][2] * sc, acc[d][3] * sc);
            float4 v1 = make_float4(acc[d][4] * sc, acc[d][5] * sc,
                                    acc[d][6] * sc, acc[d][7] * sc);
            *(float4*)(op)     = v0;
            *(float4*)(op + 4) = v1;
        }
    }
}

extern "C" void kernel_launch(void* const* d_in, const int* in_sizes, int n_in,
                              void* d_out, int out_size, void* d_ws, size_t ws_size,
                              hipStream_t stream) {
    const float* in1 = (const float*)d_in[0];
    const float* in2 = (const float*)d_in[1];
    float* out = (float*)d_out;
    dim3 grid(BATCH, HH / TY);
    corr_kernel<<<grid, NT, 0, stream>>>(in1, in2, out);
}

// Round 3
// 233.734 us; speedup vs baseline: 1.0440x; 1.0440x over previous
//
#include <hip/hip_runtime.h>

// Correlation / cost-volume, fp32.
// corr[b, dy*9+dx, y, x] = (1/128) * sum_c in1[b,c,y,x] * in2[b,c,y+dy-4,x+dx-4]
//
// R10: LDS-free. R9's counters (VALUBusy 21%, hbm 9.7%, 2625 cyc/iter vs
// ~500 cyc compute) prove the barrier-lockstep staging structure is the
// bottleneck, not load latency depth: all 5 waves sync at s_barrier and
// stall together at the same ds_read->DPP point; per-barrier fixed cost
// (~2-4K cyc) dwarfs the ~200-cyc compute payload. dx is already in-register
// (DPP x-halos); LDS only provided ~1.8x in2 / 9x in1 reuse, which L1
// (32 KB/CU, ~6 KB/block/chunk working set) serves for free.
// => drop LDS/DMA/barriers entirely. Per chunk each thread loads its own
// 32 B in2 + 32 B in1 global->register (2-stage explicit double buffer);
// waves run free, stalls overlap via TLP across ~10 waves/CU.
// HBM traffic unchanged (~176 MB incl. out); same-batch y-neighbors land on
// the same XCD (id%8) so L2 absorbs the 5x in2 halo redundancy.
// Floors: FMA 17 us, L1 ~32 us, HBM ~28 us. Target 40-80 us (from 244).

#define MAXD 4
#define ND 9
#define NDISP 81
#define BATCH 8
#define CH 128
#define HH 128
#define WW 128
#define HW (HH * WW)
#define NCHUNK CH                 // 1 channel per pipeline stage
#define TY 2
#define NT 320                    // 5 waves; threads 0..287 compute
#define NACT 288                  // (ly:2)(dy:9)(xg:16)

__device__ __forceinline__ float dpp_shr1(float x) {   // lane i <- lane i-1
    return __int_as_float(__builtin_amdgcn_update_dpp(
        0, __float_as_int(x), 0x111, 0xF, 0xF, true));
}
__device__ __forceinline__ float dpp_shl1(float x) {   // lane i <- lane i+1
    return __int_as_float(__builtin_amdgcn_update_dpp(
        0, __float_as_int(x), 0x101, 0xF, 0xF, true));
}

// launch_bounds(320,3): cap ~168 VGPR (est. use ~130-140: acc 72 + 2-stage
// w/a 32 + DPP temps + ptrs). Allows 2 blocks/CU (10 waves) without spill
// risk; spilling acc[72] to scratch would be the kill condition here.
__global__ __launch_bounds__(NT, 3) void corr_kernel(
    const float* __restrict__ in1,
    const float* __restrict__ in2,
    float* __restrict__ out)
{
    const int tid = threadIdx.x;
    if (tid >= NACT) return;      // no barriers anywhere -> early exit is safe

    const int b   = blockIdx.x;
    const int y0  = blockIdx.y * TY;
    const int xg  = tid & 15;               // 16 lanes span the 128-px row
    const int dy  = (tid >> 4) % ND;
    const int ly  = tid / 144;
    const int rl  = ly + dy;                // in2 row offset consumed
    const bool rok = (unsigned)(y0 + rl - MAXD) < (unsigned)HH;
    int r2 = y0 + rl - MAXD;                // clamped row; garbage zeroed at end
    r2 = r2 < 0 ? 0 : (r2 > HH - 1 ? HH - 1 : r2);

    const float* p2 = in2 + (size_t)b * CH * HW + (size_t)r2 * WW + xg * 8;
    const float* p1 = in1 + (size_t)b * CH * HW + (size_t)(y0 + ly) * WW + xg * 8;

    float acc[ND][8];
    #pragma unroll
    for (int d = 0; d < ND; ++d)
        #pragma unroll
        for (int i = 0; i < 8; ++i) acc[d][i] = 0.0f;

    float w0[8], a0[8], w1[8], a1[8];

    // load current chunk's 32B of in2 (w) and in1 (a), advance channel ptrs
    auto LD = [&](float* w, float* a) {
        float4 t0 = *(const float4*)(p2);
        float4 t1 = *(const float4*)(p2 + 4);
        float4 u0 = *(const float4*)(p1);
        float4 u1 = *(const float4*)(p1 + 4);
        w[0] = t0.x; w[1] = t0.y; w[2] = t0.z; w[3] = t0.w;
        w[4] = t1.x; w[5] = t1.y; w[6] = t1.z; w[7] = t1.w;
        a[0] = u0.x; a[1] = u0.y; a[2] = u0.z; a[3] = u0.w;
        a[4] = u1.x; a[5] = u1.y; a[6] = u1.z; a[7] = u1.w;
        p2 += HW; p1 += HW;
    };

    auto CMP = [&](const float* w, const float* a) {
        float W[16];
        W[0]  = dpp_shr1(w[4]);   // x-4..x-1 from lane-1; 0 at image edge
        W[1]  = dpp_shr1(w[5]);
        W[2]  = dpp_shr1(w[6]);
        W[3]  = dpp_shr1(w[7]);
        #pragma unroll
        for (int i = 0; i < 8; ++i) W[4 + i] = w[i];
        W[12] = dpp_shl1(w[0]);   // x+8..x+11 from lane+1; 0 at image edge
        W[13] = dpp_shl1(w[1]);
        W[14] = dpp_shl1(w[2]);
        W[15] = dpp_shl1(w[3]);
        #pragma unroll
        for (int d = 0; d < ND; ++d)
            #pragma unroll
            for (int i = 0; i < 8; ++i)
                acc[d][i] = fmaf(a[i], W[i + d], acc[d][i]);
    };

    // ---- software-pipelined main loop: 2 chunks per iteration ----
    LD(w0, a0);                               // chunk 0
    #pragma unroll 1
    for (int k = 0; k < NCHUNK; k += 2) {
        LD(w1, a1);                           // chunk k+1 (always < NCHUNK)
        CMP(w0, a0);                          // chunk k
        if (k + 2 < NCHUNK) LD(w0, a0);       // chunk k+2
        CMP(w1, a1);                          // chunk k+1
    }

    // ---- epilogue: mean over C; OOB rows scale to exact zero ----
    const float sc = rok ? (1.0f / (float)CH) : 0.0f;
    float* outb = out + (size_t)b * NDISP * HW
                      + (size_t)(y0 + ly) * WW + xg * 8;
    #pragma unroll
    for (int d = 0; d < ND; ++d) {
        float* op = outb + (size_t)(dy * ND + d) * HW;
        float4 v0 = make_float4(acc[d][0] * sc, acc[d][1] * sc,
                                acc[d][2] * sc, acc[d][3] * sc);
        float4 v1 = make_float4(acc[d][4] * sc, acc[d][5] * sc,
                                acc[d][6] * sc, acc[d][7] * sc);
        *(float4*)(op)     = v0;
        *(float4*)(op + 4) = v1;
    }
}

extern "C" void kernel_launch(void* const* d_in, const int* in_sizes, int n_in,
                              void* d_out, int out_size, void* d_ws, size_t ws_size,
                              hipStream_t stream) {
    const float* in1 = (const float*)d_in[0];
    const float* in2 = (const float*)d_in[1];
    float* out = (float*)d_out;
    dim3 grid(BATCH, HH / TY);
    corr_kernel<<<grid, NT, 0, stream>>>(in1, in2, out);
}

// Round 5
// 206.850 us; speedup vs baseline: 1.1797x; 1.1300x over previous
//
#include <hip/hip_runtime.h>

// Correlation / cost-volume, fp32.
// corr[b, dy*9+dx, y, x] = (1/128) * sum_c in1[b,c,y,x] * in2[b,c,y+dy-4,x+dx-4]
//
// R12 = R11 resubmitted verbatim (broker timeout, never measured).
// R11 = R10 (LDS-free, DPP x-halos, per-thread register loads) with the
// software pipeline deepened 2 -> 4 stages (prefetch 3 chunks ahead).
// R10 evidence: VALUBusy 27.7%, hbm 10%, FETCH 67 MB (= half the inputs
// re-fetched from HBM each dispatch -> avg load latency L3/HBM-class,
// ~600-900 cyc). Depth-2 gave issue->use distance ~425 SIMD-cyc < latency
// => stall-bound. Depth-4 gives ~1350 wall-cyc (3 CMPs x ~90 instr x
// 2 cyc x ~2.5 waves/SIMD) > 900 -> latency hidden, no extra traffic,
// no barriers. Cost: +32 VGPR (4x w/a stages); acc[72] stays in AGPRs.
// Tail peeled so prefetches never read past in2's allocation (b=7).
// Hand-verified: chunks 0..127 each computed once; loads capped at 127.

#define MAXD 4
#define ND 9
#define NDISP 81
#define BATCH 8
#define CH 128
#define HH 128
#define WW 128
#define HW (HH * WW)
#define NCHUNK CH                 // 1 channel per pipeline stage
#define TY 2
#define NT 320                    // 5 waves; threads 0..287 compute
#define NACT 288                  // (ly:2)(dy:9)(xg:16)

__device__ __forceinline__ float dpp_shr1(float x) {   // lane i <- lane i-1
    return __int_as_float(__builtin_amdgcn_update_dpp(
        0, __float_as_int(x), 0x111, 0xF, 0xF, true));
}
__device__ __forceinline__ float dpp_shl1(float x) {   // lane i <- lane i+1
    return __int_as_float(__builtin_amdgcn_update_dpp(
        0, __float_as_int(x), 0x101, 0xF, 0xF, true));
}

__global__ __launch_bounds__(NT, 2) void corr_kernel(
    const float* __restrict__ in1,
    const float* __restrict__ in2,
    float* __restrict__ out)
{
    const int tid = threadIdx.x;
    if (tid >= NACT) return;      // no barriers anywhere -> early exit is safe

    const int b   = blockIdx.x;
    const int y0  = blockIdx.y * TY;
    const int xg  = tid & 15;               // 16 lanes span the 128-px row
    const int dy  = (tid >> 4) % ND;
    const int ly  = tid / 144;
    const int rl  = ly + dy;                // in2 row offset consumed
    const bool rok = (unsigned)(y0 + rl - MAXD) < (unsigned)HH;
    int r2 = y0 + rl - MAXD;                // clamped row; garbage zeroed at end
    r2 = r2 < 0 ? 0 : (r2 > HH - 1 ? HH - 1 : r2);

    const float* p2 = in2 + (size_t)b * CH * HW + (size_t)r2 * WW + xg * 8;
    const float* p1 = in1 + (size_t)b * CH * HW + (size_t)(y0 + ly) * WW + xg * 8;

    float acc[ND][8];
    #pragma unroll
    for (int d = 0; d < ND; ++d)
        #pragma unroll
        for (int i = 0; i < 8; ++i) acc[d][i] = 0.0f;

    // 4 named pipeline stages (static indexing only -> registers, rule #20)
    float w0[8], a0[8], w1[8], a1[8], w2[8], a2[8], w3[8], a3[8];

    // load current chunk's 32B of in2 (w) and 32B of in1 (a); advance ptrs
    auto LD = [&](float* w, float* a) {
        float4 t0 = *(const float4*)(p2);
        float4 t1 = *(const float4*)(p2 + 4);
        float4 u0 = *(const float4*)(p1);
        float4 u1 = *(const float4*)(p1 + 4);
        w[0] = t0.x; w[1] = t0.y; w[2] = t0.z; w[3] = t0.w;
        w[4] = t1.x; w[5] = t1.y; w[6] = t1.z; w[7] = t1.w;
        a[0] = u0.x; a[1] = u0.y; a[2] = u0.z; a[3] = u0.w;
        a[4] = u1.x; a[5] = u1.y; a[6] = u1.z; a[7] = u1.w;
        p2 += HW; p1 += HW;
    };

    auto CMP = [&](const float* w, const float* a) {
        float W[16];
        W[0]  = dpp_shr1(w[4]);   // x-4..x-1 from lane-1; 0 at image edge
        W[1]  = dpp_shr1(w[5]);
        W[2]  = dpp_shr1(w[6]);
        W[3]  = dpp_shr1(w[7]);
        #pragma unroll
        for (int i = 0; i < 8; ++i) W[4 + i] = w[i];
        W[12] = dpp_shl1(w[0]);   // x+8..x+11 from lane+1; 0 at image edge
        W[13] = dpp_shl1(w[1]);
        W[14] = dpp_shl1(w[2]);
        W[15] = dpp_shl1(w[3]);
        #pragma unroll
        for (int d = 0; d < ND; ++d)
            #pragma unroll
            for (int i = 0; i < 8; ++i)
                acc[d][i] = fmaf(a[i], W[i + d], acc[d][i]);
    };

    // ---- depth-4 software pipeline: 4 chunks per iteration ----
    LD(w0, a0);                   // chunk 0
    LD(w1, a1);                   // chunk 1
    LD(w2, a2);                   // chunk 2
    #pragma unroll 1
    for (int k = 0; k <= NCHUNK - 8; k += 4) {   // k = 0,4,...,120
        LD(w3, a3);  CMP(w0, a0); // load k+3, compute k
        LD(w0, a0);  CMP(w1, a1); // load k+4, compute k+1
        LD(w1, a1);  CMP(w2, a2); // load k+5, compute k+2
        LD(w2, a2);  CMP(w3, a3); // load k+6, compute k+3
    }
    // tail (k=124): stages hold 124,125,126; one last in-bounds load of 127
    LD(w3, a3);
    CMP(w0, a0); CMP(w1, a1); CMP(w2, a2); CMP(w3, a3);

    // ---- epilogue: mean over C; OOB rows scale to exact zero ----
    const float sc = rok ? (1.0f / (float)CH) : 0.0f;
    float* outb = out + (size_t)b * NDISP * HW
                      + (size_t)(y0 + ly) * WW + xg * 8;
    #pragma unroll
    for (int d = 0; d < ND; ++d) {
        float* op = outb + (size_t)(dy * ND + d) * HW;
        float4 v0 = make_float4(acc[d][0] * sc, acc[d][1] * sc,
                                acc[d][2] * sc, acc[d][3] * sc);
        float4 v1 = make_float4(acc[d][4] * sc, acc[d][5] * sc,
                                acc[d][6] * sc, acc[d][7] * sc);
        *(float4*)(op)     = v0;
        *(float4*)(op + 4) = v1;
    }
}

extern "C" void kernel_launch(void* const* d_in, const int* in_sizes, int n_in,
                              void* d_out, int out_size, void* d_ws, size_t ws_size,
                              hipStream_t stream) {
    const float* in1 = (const float*)d_in[0];
    const float* in2 = (const float*)d_in[1];
    float* out = (float*)d_out;
    dim3 grid(BATCH, HH / TY);
    corr_kernel<<<grid, NT, 0, stream>>>(in1, in2, out);
}